// Round 6
// baseline (282.339 us; speedup 1.0000x reference)
//
#include <hip/hip_runtime.h>
#include <math.h>

#define Bn 2
#define Hn 12
#define Tn 512
#define Cn 768
#define HS 64
#define BH 24
#define MTOP 8
#define NCOMB 36
#define NEGV -1e30f

typedef __bf16 bf16x8 __attribute__((ext_vector_type(8)));
typedef float f32x4 __attribute__((ext_vector_type(4)));

// combo tables: slots (0..7) for size-1 (8 combos) then size-2 (28 combos), lexicographic
__device__ __constant__ int C_SL0[NCOMB] = {
  0,1,2,3,4,5,6,7,
  0,0,0,0,0,0,0,
  1,1,1,1,1,1,
  2,2,2,2,2,
  3,3,3,3,
  4,4,4,
  5,5,
  6};
__device__ __constant__ int C_SL1[NCOMB] = {
  -1,-1,-1,-1,-1,-1,-1,-1,
  1,2,3,4,5,6,7,
  2,3,4,5,6,7,
  3,4,5,6,7,
  4,5,6,7,
  5,6,7,
  6,7,
  7};

// gram pair tables: 45 pairs (a<=b) over 9 tokens
__device__ __constant__ int PA[45] = {
  0,0,0,0,0,0,0,0,0,
  1,1,1,1,1,1,1,1,
  2,2,2,2,2,2,2,
  3,3,3,3,3,3,
  4,4,4,4,4,
  5,5,5,5,
  6,6,6,
  7,7,
  8};
__device__ __constant__ int PB[45] = {
  0,1,2,3,4,5,6,7,8,
  1,2,3,4,5,6,7,8,
  2,3,4,5,6,7,8,
  3,4,5,6,7,8,
  4,5,6,7,8,
  5,6,7,8,
  6,7,8,
  7,8,
  8};

__device__ __forceinline__ unsigned short bf_rne(float x) {
    unsigned u = __float_as_uint(x);
    return (unsigned short)((u + 0x7fff + ((u >> 16) & 1)) >> 16);
}

// ---------------- fp32 -> (bf16 hi, bf16 lo) split ------------------------------------
__global__ __launch_bounds__(256) void conv_split(const float* __restrict__ s,
                                                  unsigned short* __restrict__ hi,
                                                  unsigned short* __restrict__ lo, int n) {
    int idx = blockIdx.x * 256 + threadIdx.x;
    if (idx < n) {
        float x = s[idx];
        unsigned short h = bf_rne(x);
        float hf = __uint_as_float(((unsigned)h) << 16);
        hi[idx] = h;
        lo[idx] = bf_rne(x - hf);
    }
}

// ---------------- fp32 -> bf16 (RNE) --------------------------------------------------
__global__ __launch_bounds__(256) void conv_bf(const float* __restrict__ s,
                                               unsigned short* __restrict__ d, int n) {
    int idx = blockIdx.x * 256 + threadIdx.x;
    if (idx < n) d[idx] = bf_rne(s[idx]);
}

// ---------------- 3-term split-bf16 MFMA qkv GEMM -------------------------------------
// C = (Ahi+Alo)@(Bhi+Blo)^T + bias, dropping lo*lo (error ~2^-18 rel ~ fp32 noise).
// A: x [1024][768], B: W_attn [2304][768]. Output scattered fp32 per-head q/k/v.
__global__ __launch_bounds__(256) void mfma_qkv(const unsigned short* __restrict__ Ahi,
                                                const unsigned short* __restrict__ Alo,
                                                const unsigned short* __restrict__ Bhi,
                                                const unsigned short* __restrict__ Blo,
                                                const float* __restrict__ bias,
                                                float* __restrict__ qh,
                                                float* __restrict__ kh,
                                                float* __restrict__ vh) {
    const int wv = threadIdx.x >> 6;
    const int lane = threadIdx.x & 63;
    const int tn = blockIdx.x * 64;
    const int m0 = blockIdx.y * 64 + (wv >> 1) * 32;
    const int n0 = tn + (wv & 1) * 32;
    const int r = lane & 15;
    const int kq = lane >> 4;
    f32x4 acc[2][2] = {};
    const size_t ao0 = (size_t)(m0 + r) * Cn + kq * 8;
    const size_t ao1 = ao0 + 16 * Cn;
    const size_t bo0 = (size_t)(n0 + r) * Cn + kq * 8;
    const size_t bo1 = bo0 + 16 * Cn;
    for (int k = 0; k < Cn; k += 32) {
        bf16x8 a0h = *(const bf16x8*)(Ahi + ao0 + k);
        bf16x8 a1h = *(const bf16x8*)(Ahi + ao1 + k);
        bf16x8 a0l = *(const bf16x8*)(Alo + ao0 + k);
        bf16x8 a1l = *(const bf16x8*)(Alo + ao1 + k);
        bf16x8 b0h = *(const bf16x8*)(Bhi + bo0 + k);
        bf16x8 b1h = *(const bf16x8*)(Bhi + bo1 + k);
        bf16x8 b0l = *(const bf16x8*)(Blo + bo0 + k);
        bf16x8 b1l = *(const bf16x8*)(Blo + bo1 + k);
        acc[0][0] = __builtin_amdgcn_mfma_f32_16x16x32_bf16(a0h, b0h, acc[0][0], 0, 0, 0);
        acc[0][1] = __builtin_amdgcn_mfma_f32_16x16x32_bf16(a0h, b1h, acc[0][1], 0, 0, 0);
        acc[1][0] = __builtin_amdgcn_mfma_f32_16x16x32_bf16(a1h, b0h, acc[1][0], 0, 0, 0);
        acc[1][1] = __builtin_amdgcn_mfma_f32_16x16x32_bf16(a1h, b1h, acc[1][1], 0, 0, 0);
        acc[0][0] = __builtin_amdgcn_mfma_f32_16x16x32_bf16(a0h, b0l, acc[0][0], 0, 0, 0);
        acc[0][1] = __builtin_amdgcn_mfma_f32_16x16x32_bf16(a0h, b1l, acc[0][1], 0, 0, 0);
        acc[1][0] = __builtin_amdgcn_mfma_f32_16x16x32_bf16(a1h, b0l, acc[1][0], 0, 0, 0);
        acc[1][1] = __builtin_amdgcn_mfma_f32_16x16x32_bf16(a1h, b1l, acc[1][1], 0, 0, 0);
        acc[0][0] = __builtin_amdgcn_mfma_f32_16x16x32_bf16(a0l, b0h, acc[0][0], 0, 0, 0);
        acc[0][1] = __builtin_amdgcn_mfma_f32_16x16x32_bf16(a0l, b1h, acc[0][1], 0, 0, 0);
        acc[1][0] = __builtin_amdgcn_mfma_f32_16x16x32_bf16(a1l, b0h, acc[1][0], 0, 0, 0);
        acc[1][1] = __builtin_amdgcn_mfma_f32_16x16x32_bf16(a1l, b1h, acc[1][1], 0, 0, 0);
    }
    // D mapping: col = lane&15 (n), row = (lane>>4)*4 + rr (m)
    const int part = tn / Cn;                  // 0=q,1=k,2=v (64-tile never crosses parts)
    float* dst = (part == 0) ? qh : ((part == 1) ? kh : vh);
    #pragma unroll
    for (int im = 0; im < 2; ++im) {
        #pragma unroll
        for (int in = 0; in < 2; ++in) {
            #pragma unroll
            for (int rr = 0; rr < 4; ++rr) {
                int mm = m0 + im * 16 + kq * 4 + rr;
                int nn = n0 + in * 16 + r;
                float val = acc[im][in][rr] + bias[nn];
                int bb = mm >> 9, t = mm & 511;
                int c = nn - part * Cn;
                int h = c >> 6, d = c & 63;
                dst[((size_t)((bb * Hn) + h) * Tn + t) * HS + d] = val;
            }
        }
    }
}

// ---------------- bf16 MFMA GEMM (single-term): out = A @ B^T + bias, flat ------------
__global__ __launch_bounds__(256) void mfma_proj(const unsigned short* __restrict__ Abf,
                                                 const unsigned short* __restrict__ Bbf,
                                                 const float* __restrict__ bias,
                                                 float* __restrict__ outp,
                                                 int M, int N, int K) {
    const int wv = threadIdx.x >> 6;
    const int lane = threadIdx.x & 63;
    const int m0 = blockIdx.y * 64 + (wv >> 1) * 32;
    const int n0 = blockIdx.x * 64 + (wv & 1) * 32;
    const int r = lane & 15;
    const int kq = lane >> 4;
    f32x4 acc[2][2] = {};
    const unsigned short* arow0 = Abf + (size_t)(m0 + r) * K + kq * 8;
    const unsigned short* arow1 = arow0 + 16 * K;
    const unsigned short* brow0 = Bbf + (size_t)(n0 + r) * K + kq * 8;
    const unsigned short* brow1 = brow0 + 16 * K;
    for (int k = 0; k < K; k += 32) {
        bf16x8 a0 = *(const bf16x8*)(arow0 + k);
        bf16x8 a1 = *(const bf16x8*)(arow1 + k);
        bf16x8 b0 = *(const bf16x8*)(brow0 + k);
        bf16x8 b1 = *(const bf16x8*)(brow1 + k);
        acc[0][0] = __builtin_amdgcn_mfma_f32_16x16x32_bf16(a0, b0, acc[0][0], 0, 0, 0);
        acc[0][1] = __builtin_amdgcn_mfma_f32_16x16x32_bf16(a0, b1, acc[0][1], 0, 0, 0);
        acc[1][0] = __builtin_amdgcn_mfma_f32_16x16x32_bf16(a1, b0, acc[1][0], 0, 0, 0);
        acc[1][1] = __builtin_amdgcn_mfma_f32_16x16x32_bf16(a1, b1, acc[1][1], 0, 0, 0);
    }
    #pragma unroll
    for (int im = 0; im < 2; ++im)
        #pragma unroll
        for (int in = 0; in < 2; ++in)
            #pragma unroll
            for (int rr = 0; rr < 4; ++rr) {
                int mm = m0 + im * 16 + kq * 4 + rr;
                int nn = n0 + in * 16 + r;
                outp[(size_t)mm * N + nn] = acc[im][in][rr] + bias[nn];
            }
}

// ---------------- DPP selection: one WAVE per token, 4 tokens/block -------------------
// LDS union: Klds (sim phase, 17.4 KB) overlays tail structs (22.9 KB) -> 7 blocks/CU.
// Tail LDS is per-wave private -> no block barriers after the sim loop.
__global__ __launch_bounds__(256, 7) void dpp_kernel(const float* __restrict__ qh,
                                                     const float* __restrict__ kh,
                                                     const float* __restrict__ vh,
                                                     unsigned short* __restrict__ yb) {
    const int bh = blockIdx.x;
    const int i0 = blockIdx.y * 4;
    const int w = threadIdx.x >> 6;
    const int lane = threadIdx.x & 63;
    const int i = i0 + w;

    __shared__ __align__(16) char smem[22944];
    float (*Klds)[68] = (float (*)[68])smem;                           // phase 1 only
    float (*KshW)[68] = (float (*)[68])(smem + 2448 * w);              // [0,9792)
    float (*VshW)[65] = (float (*)[65])(smem + 9792 + 2340 * w);       // [9792,19152)
    float* GshW       = (float*)(smem + 19152 + 324 * w);              // [19152,20448)
    float* qdW        = (float*)(smem + 20448 + 48 * w);               // [20448,20640)
    float (*PWW)[4]   = (float (*)[4])(smem + 20640 + 576 * w);        // [20640,22944)

    const float* qp    = qh + (size_t)(bh * Tn + i) * HS;
    const float* kbase = kh + (size_t)bh * Tn * HS;
    const float* vbase = vh + (size_t)bh * Tn * HS;

    // q_i resident in registers for the whole sim phase
    float4 qv[16];
    #pragma unroll
    for (int t = 0; t < 16; ++t) qv[t] = ((const float4*)qp)[t];

    float sv[8];
    #pragma unroll
    for (int r = 0; r < 8; ++r) sv[r] = -INFINITY;

    const int cmax = (i0 + 3) >> 6;    // block-uniform
    const int rmax = i >> 6;

    // software-pipelined chunk staging: prefetch chunk c+1 while computing chunk c
    float4 pre[4];
    {
        const float4* src = (const float4*)kbase;
        #pragma unroll
        for (int u = 0; u < 4; ++u) pre[u] = src[threadIdx.x + u * 256];
    }
    #pragma unroll
    for (int c = 0; c < 8; ++c) {
        if (c <= cmax) {
            #pragma unroll
            for (int u = 0; u < 4; ++u) {
                int e = threadIdx.x + u * 256;
                *(float4*)&Klds[e >> 4][(e & 15) * 4] = pre[u];
            }
            __syncthreads();
            if (c + 1 <= cmax) {
                const float4* src = (const float4*)(kbase + (size_t)(c + 1) * 64 * HS);
                #pragma unroll
                for (int u = 0; u < 4; ++u) pre[u] = src[threadIdx.x + u * 256];
            }
            if (c <= rmax) {
                const int j = c * 64 + lane;
                const float4* kr = (const float4*)&Klds[lane][0];
                float acc = 0.f;
                #pragma unroll
                for (int t = 0; t < 16; ++t) {
                    float4 kv = kr[t];
                    acc += kv.x * qv[t].x; acc += kv.y * qv[t].y;
                    acc += kv.z * qv[t].z; acc += kv.w * qv[t].w;
                }
                sv[c] = (j <= i) ? acc : -INFINITY;
            }
            __syncthreads();   // last barrier in the kernel: after this, Klds is dead
        }
    }

    // qd0 = sim[i] = k_i . q_i
    float qd0 = 0.f;
    #pragma unroll
    for (int c = 0; c < 8; ++c) {
        float t = __shfl(sv[c], i & 63, 64);
        if (c == rmax) qd0 = t;
    }

    // top-8: 8 in-register butterfly argmax passes (value desc, tie -> lower index)
    float topv[8]; int topi[8];
    #pragma unroll
    for (int p = 0; p < MTOP; ++p) {
        float bv = -INFINITY; int bi = 0x7fffffff;
        #pragma unroll
        for (int r = 0; r < 8; ++r) {
            int j = r * 64 + lane;
            float v = sv[r];
            if (v > bv || (v == bv && j < bi)) { bv = v; bi = j; }
        }
        #pragma unroll
        for (int off = 32; off > 0; off >>= 1) {
            float ov = __shfl_xor(bv, off, 64);
            int   oi = __shfl_xor(bi, off, 64);
            if (ov > bv || (ov == bv && oi < bi)) { bv = ov; bi = oi; }
        }
        topv[p] = bv; topi[p] = bi;
        const int rs = bi >> 6, ls = bi & 63;
        #pragma unroll
        for (int r = 0; r < 8; ++r)
            if (r == rs && lane == ls) sv[r] = -INFINITY;
    }

    // validity bitmask per slot (wave-uniform)
    const int n_cand = (i + 1 < MTOP) ? (i + 1) : MTOP;
    int vmask = 0;
    #pragma unroll
    for (int s = 0; s < MTOP; ++s)
        if (s < n_cand && topi[s] != i) vmask |= (1 << s);

    // stage selected K/V rows {i} U top_idx into per-wave LDS (coalesced, lane = d)
    #pragma unroll
    for (int a = 0; a < 9; ++a) {
        int t = (a == 0) ? i : topi[a - 1];
        KshW[a][lane] = kbase[(size_t)t * HS + lane];
        VshW[a][lane] = vbase[(size_t)t * HS + lane];
    }
    if (lane < 9) {
        float val = qd0;
        #pragma unroll
        for (int p = 0; p < 8; ++p) if (lane == p + 1) val = topv[p];
        qdW[lane] = val;
    }

    // gram: lane l < 45 computes pair (PA[l], PB[l])  (per-wave LDS, no barrier needed)
    if (lane < 45) {
        const int a = PA[lane], b = PB[lane];
        const float4* rka = (const float4*)&KshW[a][0];
        const float4* rkb = (const float4*)&KshW[b][0];
        float acc = 0.f;
        #pragma unroll
        for (int t = 0; t < 16; ++t) {
            float4 fa = rka[t], fb = rkb[t];
            acc += fa.x * fb.x; acc += fa.y * fb.y;
            acc += fa.z * fb.z; acc += fa.w * fb.w;
        }
        GshW[a * 9 + b] = acc;
        GshW[b * 9 + a] = acc;
    }

    // combos on lanes 0..35
    float score = -INFINITY;
    int ca = 0, cb = 0, sdim = 1;
    if (lane < NCOMB) {
        const int sl0 = C_SL0[lane], sl1 = C_SL1[lane];
        sdim = (sl1 < 0) ? 1 : 2;
        ca = sl0 + 1;
        cb = (sl1 < 0) ? 0 : sl1 + 1;
        bool valid = ((vmask >> sl0) & 1);
        if (sdim == 2) valid = valid && ((vmask >> sl1) & 1);
        float G00 = GshW[0];
        float Gaa = GshW[ca * 9 + ca];
        float G0a = GshW[ca];
        float det;
        if (sdim == 1) {
            det = G00 * Gaa - G0a * G0a;
        } else {
            float G0b = GshW[cb];
            float Gab = GshW[ca * 9 + cb];
            float Gbb = GshW[cb * 9 + cb];
            det = G00 * (Gaa * Gbb - Gab * Gab)
                - G0a * (G0a * Gbb - Gab * G0b)
                + G0b * (G0a * Gab - Gaa * G0b);
        }
        score = valid ? (logf(det + 1e-6f) / (float)(sdim + 1)) : NEGV;
    }
    // softmax over scores via butterfly (lanes>=36 contribute -inf / 0)
    float mx = score;
    #pragma unroll
    for (int off = 32; off > 0; off >>= 1) mx = fmaxf(mx, __shfl_xor(mx, off, 64));
    float e = (lane < NCOMB) ? expf(score - mx) : 0.f;
    float sum = e;
    #pragma unroll
    for (int off = 32; off > 0; off >>= 1) sum += __shfl_xor(sum, off, 64);
    const bool hasValid = (mx > -1e29f);

    if (lane < NCOMB) {
        float prob = e / sum;
        float d0 = qdW[0]  * 0.125f;
        float d1 = qdW[ca] * 0.125f;
        float d2 = (sdim == 2) ? qdW[cb] * 0.125f : -INFINITY;
        float m2 = fmaxf(fmaxf(d0, d1), d2);
        float e0 = expf(d0 - m2), e1 = expf(d1 - m2);
        float e2 = (sdim == 2) ? expf(d2 - m2) : 0.f;
        float inv = prob / (e0 + e1 + e2);
        float4 pw = {e0 * inv, e1 * inv, e2 * inv, 0.f};
        *(float4*)&PWW[lane][0] = pw;
    }

    // y[d], d = lane (per-wave LDS reads; in-wave ordering only)
    const float v0 = VshW[0][lane];
    float y;
    if (!hasValid) {
        y = v0;
    } else {
        float acc = 0.f;
        #pragma unroll
        for (int c = 0; c < NCOMB; ++c) {
            float4 pw = *(const float4*)&PWW[c][0];
            int a = C_SL0[c] + 1;
            int b = (C_SL1[c] < 0) ? 0 : C_SL1[c] + 1;   // pw.z == 0 when sdim==1
            acc += pw.x * v0 + pw.y * VshW[a][lane] + pw.z * VshW[b][lane];
        }
        y = acc;
    }
    const int bb = bh / Hn, h = bh % Hn;
    yb[((size_t)(bb * Tn + i)) * Cn + h * HS + lane] = bf_rne(y);
}

extern "C" void kernel_launch(void* const* d_in, const int* in_sizes, int n_in,
                              void* d_out, int out_size, void* d_ws, size_t ws_size,
                              hipStream_t stream) {
    const float* x      = (const float*)d_in[0];
    const float* W_attn = (const float*)d_in[1];
    const float* b_attn = (const float*)d_in[2];
    const float* W_proj = (const float*)d_in[3];
    const float* b_proj = (const float*)d_in[4];
    float* out = (float*)d_out;

    char* ws = (char*)d_ws;
    float* qh = (float*)(ws);                              // 3 MB
    float* kh = (float*)(ws + 3145728);                    // 3 MB
    float* vh = (float*)(ws + 6291456);                    // 3 MB
    unsigned short* xhi = (unsigned short*)(ws + 9437184); // 1.5 MB
    unsigned short* xlo = (unsigned short*)(ws + 11010048);// 1.5 MB
    unsigned short* Whi = (unsigned short*)(ws + 12582912);// 3.375 MB
    unsigned short* Wlo = (unsigned short*)(ws + 16121856);// 3.375 MB -> 18.75 MB total
    unsigned short* ybf  = xhi;  // xhi dead after mfma_qkv
    unsigned short* Wpbf = xlo;  // xlo dead after mfma_qkv

    const int NX = Bn * Tn * Cn;   // 786432
    const int NW = 3 * Cn * Cn;    // 1769472
    const int NP = Cn * Cn;        // 589824

    // 1) split-convert x and W_attn to bf16 hi/lo
    conv_split<<<dim3((NX + 255) / 256), 256, 0, stream>>>(x, xhi, xlo, NX);
    conv_split<<<dim3((NW + 255) / 256), 256, 0, stream>>>(W_attn, Whi, Wlo, NW);

    // 2) qkv = x @ W_attn^T + b via 3-term split-bf16 MFMA, scatter to per-head fp32
    mfma_qkv<<<dim3(36, 16), 256, 0, stream>>>(xhi, xlo, Whi, Wlo, b_attn, qh, kh, vh);

    // 3) convert W_proj to bf16 (into xlo region, now dead)
    conv_bf<<<dim3((NP + 255) / 256), 256, 0, stream>>>(W_proj, Wpbf, NP);

    // 4) dpp: one wave per (head, token); writes y bf16 into xhi region (now dead)
    dpp_kernel<<<dim3(BH, Tn / 4), 256, 0, stream>>>(qh, kh, vh, ybf);

    // 5) out = y @ Wp^T + bp via bf16 MFMA
    mfma_proj<<<dim3(12, 16), 256, 0, stream>>>(ybf, Wpbf, b_proj, out, Bn * Tn, Cn, Cn);
}

// Round 7
// 240.972 us; speedup vs baseline: 1.1717x; 1.1717x over previous
//
#include <hip/hip_runtime.h>
#include <math.h>

#define Bn 2
#define Hn 12
#define Tn 512
#define Cn 768
#define HS 64
#define BH 24
#define MTOP 8
#define NCOMB 36
#define NEGV -1e30f

typedef __bf16 bf16x8 __attribute__((ext_vector_type(8)));
typedef float f32x4 __attribute__((ext_vector_type(4)));

// combo tables: slots (0..7) for size-1 (8 combos) then size-2 (28 combos), lexicographic
__device__ __constant__ int C_SL0[NCOMB] = {
  0,1,2,3,4,5,6,7,
  0,0,0,0,0,0,0,
  1,1,1,1,1,1,
  2,2,2,2,2,
  3,3,3,3,
  4,4,4,
  5,5,
  6};
__device__ __constant__ int C_SL1[NCOMB] = {
  -1,-1,-1,-1,-1,-1,-1,-1,
  1,2,3,4,5,6,7,
  2,3,4,5,6,7,
  3,4,5,6,7,
  4,5,6,7,
  5,6,7,
  6,7,
  7};

// gram pair tables: 45 pairs (a<=b) over 9 tokens
__device__ __constant__ int PA[45] = {
  0,0,0,0,0,0,0,0,0,
  1,1,1,1,1,1,1,1,
  2,2,2,2,2,2,2,
  3,3,3,3,3,3,
  4,4,4,4,4,
  5,5,5,5,
  6,6,6,
  7,7,
  8};
__device__ __constant__ int PB[45] = {
  0,1,2,3,4,5,6,7,8,
  1,2,3,4,5,6,7,8,
  2,3,4,5,6,7,8,
  3,4,5,6,7,8,
  4,5,6,7,8,
  5,6,7,8,
  6,7,8,
  7,8,
  8};

__device__ __forceinline__ unsigned short bf_rne(float x) {
    unsigned u = __float_as_uint(x);
    return (unsigned short)((u + 0x7fff + ((u >> 16) & 1)) >> 16);
}

// ---------------- fp32 -> (bf16 hi, bf16 lo) split ------------------------------------
__global__ __launch_bounds__(256) void conv_split(const float* __restrict__ s,
                                                  unsigned short* __restrict__ hi,
                                                  unsigned short* __restrict__ lo, int n) {
    int idx = blockIdx.x * 256 + threadIdx.x;
    if (idx < n) {
        float x = s[idx];
        unsigned short h = bf_rne(x);
        float hf = __uint_as_float(((unsigned)h) << 16);
        hi[idx] = h;
        lo[idx] = bf_rne(x - hf);
    }
}

// ---------------- fp32 -> bf16 (RNE) --------------------------------------------------
__global__ __launch_bounds__(256) void conv_bf(const float* __restrict__ s,
                                               unsigned short* __restrict__ d, int n) {
    int idx = blockIdx.x * 256 + threadIdx.x;
    if (idx < n) d[idx] = bf_rne(s[idx]);
}

// ---------------- 3-term split-bf16 MFMA qkv GEMM -------------------------------------
// C = (Ahi+Alo)@(Bhi+Blo)^T + bias, dropping lo*lo (error ~2^-18 rel ~ fp32 noise).
// A: x [1024][768], B: W_attn [2304][768]. Output scattered fp32 per-head q/k/v.
__global__ __launch_bounds__(256) void mfma_qkv(const unsigned short* __restrict__ Ahi,
                                                const unsigned short* __restrict__ Alo,
                                                const unsigned short* __restrict__ Bhi,
                                                const unsigned short* __restrict__ Blo,
                                                const float* __restrict__ bias,
                                                float* __restrict__ qh,
                                                float* __restrict__ kh,
                                                float* __restrict__ vh) {
    const int wv = threadIdx.x >> 6;
    const int lane = threadIdx.x & 63;
    const int tn = blockIdx.x * 64;
    const int m0 = blockIdx.y * 64 + (wv >> 1) * 32;
    const int n0 = tn + (wv & 1) * 32;
    const int r = lane & 15;
    const int kq = lane >> 4;
    f32x4 acc[2][2] = {};
    const size_t ao0 = (size_t)(m0 + r) * Cn + kq * 8;
    const size_t ao1 = ao0 + 16 * Cn;
    const size_t bo0 = (size_t)(n0 + r) * Cn + kq * 8;
    const size_t bo1 = bo0 + 16 * Cn;
    for (int k = 0; k < Cn; k += 32) {
        bf16x8 a0h = *(const bf16x8*)(Ahi + ao0 + k);
        bf16x8 a1h = *(const bf16x8*)(Ahi + ao1 + k);
        bf16x8 a0l = *(const bf16x8*)(Alo + ao0 + k);
        bf16x8 a1l = *(const bf16x8*)(Alo + ao1 + k);
        bf16x8 b0h = *(const bf16x8*)(Bhi + bo0 + k);
        bf16x8 b1h = *(const bf16x8*)(Bhi + bo1 + k);
        bf16x8 b0l = *(const bf16x8*)(Blo + bo0 + k);
        bf16x8 b1l = *(const bf16x8*)(Blo + bo1 + k);
        acc[0][0] = __builtin_amdgcn_mfma_f32_16x16x32_bf16(a0h, b0h, acc[0][0], 0, 0, 0);
        acc[0][1] = __builtin_amdgcn_mfma_f32_16x16x32_bf16(a0h, b1h, acc[0][1], 0, 0, 0);
        acc[1][0] = __builtin_amdgcn_mfma_f32_16x16x32_bf16(a1h, b0h, acc[1][0], 0, 0, 0);
        acc[1][1] = __builtin_amdgcn_mfma_f32_16x16x32_bf16(a1h, b1h, acc[1][1], 0, 0, 0);
        acc[0][0] = __builtin_amdgcn_mfma_f32_16x16x32_bf16(a0h, b0l, acc[0][0], 0, 0, 0);
        acc[0][1] = __builtin_amdgcn_mfma_f32_16x16x32_bf16(a0h, b1l, acc[0][1], 0, 0, 0);
        acc[1][0] = __builtin_amdgcn_mfma_f32_16x16x32_bf16(a1h, b0l, acc[1][0], 0, 0, 0);
        acc[1][1] = __builtin_amdgcn_mfma_f32_16x16x32_bf16(a1h, b1l, acc[1][1], 0, 0, 0);
        acc[0][0] = __builtin_amdgcn_mfma_f32_16x16x32_bf16(a0l, b0h, acc[0][0], 0, 0, 0);
        acc[0][1] = __builtin_amdgcn_mfma_f32_16x16x32_bf16(a0l, b1h, acc[0][1], 0, 0, 0);
        acc[1][0] = __builtin_amdgcn_mfma_f32_16x16x32_bf16(a1l, b0h, acc[1][0], 0, 0, 0);
        acc[1][1] = __builtin_amdgcn_mfma_f32_16x16x32_bf16(a1l, b1h, acc[1][1], 0, 0, 0);
    }
    // D mapping: col = lane&15 (n), row = (lane>>4)*4 + rr (m)
    const int part = tn / Cn;                  // 0=q,1=k,2=v (64-tile never crosses parts)
    float* dst = (part == 0) ? qh : ((part == 1) ? kh : vh);
    #pragma unroll
    for (int im = 0; im < 2; ++im) {
        #pragma unroll
        for (int in = 0; in < 2; ++in) {
            #pragma unroll
            for (int rr = 0; rr < 4; ++rr) {
                int mm = m0 + im * 16 + kq * 4 + rr;
                int nn = n0 + in * 16 + r;
                float val = acc[im][in][rr] + bias[nn];
                int bb = mm >> 9, t = mm & 511;
                int c = nn - part * Cn;
                int h = c >> 6, d = c & 63;
                dst[((size_t)((bb * Hn) + h) * Tn + t) * HS + d] = val;
            }
        }
    }
}

// ---------------- bf16 MFMA GEMM (single-term): out = A @ B^T + bias, flat ------------
__global__ __launch_bounds__(256) void mfma_proj(const unsigned short* __restrict__ Abf,
                                                 const unsigned short* __restrict__ Bbf,
                                                 const float* __restrict__ bias,
                                                 float* __restrict__ outp,
                                                 int M, int N, int K) {
    const int wv = threadIdx.x >> 6;
    const int lane = threadIdx.x & 63;
    const int m0 = blockIdx.y * 64 + (wv >> 1) * 32;
    const int n0 = blockIdx.x * 64 + (wv & 1) * 32;
    const int r = lane & 15;
    const int kq = lane >> 4;
    f32x4 acc[2][2] = {};
    const unsigned short* arow0 = Abf + (size_t)(m0 + r) * K + kq * 8;
    const unsigned short* arow1 = arow0 + 16 * K;
    const unsigned short* brow0 = Bbf + (size_t)(n0 + r) * K + kq * 8;
    const unsigned short* brow1 = brow0 + 16 * K;
    for (int k = 0; k < K; k += 32) {
        bf16x8 a0 = *(const bf16x8*)(arow0 + k);
        bf16x8 a1 = *(const bf16x8*)(arow1 + k);
        bf16x8 b0 = *(const bf16x8*)(brow0 + k);
        bf16x8 b1 = *(const bf16x8*)(brow1 + k);
        acc[0][0] = __builtin_amdgcn_mfma_f32_16x16x32_bf16(a0, b0, acc[0][0], 0, 0, 0);
        acc[0][1] = __builtin_amdgcn_mfma_f32_16x16x32_bf16(a0, b1, acc[0][1], 0, 0, 0);
        acc[1][0] = __builtin_amdgcn_mfma_f32_16x16x32_bf16(a1, b0, acc[1][0], 0, 0, 0);
        acc[1][1] = __builtin_amdgcn_mfma_f32_16x16x32_bf16(a1, b1, acc[1][1], 0, 0, 0);
    }
    #pragma unroll
    for (int im = 0; im < 2; ++im)
        #pragma unroll
        for (int in = 0; in < 2; ++in)
            #pragma unroll
            for (int rr = 0; rr < 4; ++rr) {
                int mm = m0 + im * 16 + kq * 4 + rr;
                int nn = n0 + in * 16 + r;
                outp[(size_t)mm * N + nn] = acc[im][in][rr] + bias[nn];
            }
}

// ---------------- DPP selection: one WAVE per token, 4 tokens/block -------------------
// LDS union: Klds (sim phase, 17.4 KB) overlays tail structs (22.9 KB) -> 7 blocks/CU
// by LDS. NOTE: no min-waves launch bound — r6's (256,7) capped VGPRs at ~36 and
// spilled ~35 KB/wave to scratch (WRITE_SIZE 47->291 MB, dpp 94->138 us). Let the
// compiler use its natural ~52 VGPRs; LDS is the occupancy limiter.
__global__ __launch_bounds__(256) void dpp_kernel(const float* __restrict__ qh,
                                                  const float* __restrict__ kh,
                                                  const float* __restrict__ vh,
                                                  unsigned short* __restrict__ yb) {
    const int bh = blockIdx.x;
    const int i0 = blockIdx.y * 4;
    const int w = threadIdx.x >> 6;
    const int lane = threadIdx.x & 63;
    const int i = i0 + w;

    __shared__ __align__(16) char smem[22944];
    float (*Klds)[68] = (float (*)[68])smem;                           // phase 1 only
    float (*KshW)[68] = (float (*)[68])(smem + 2448 * w);              // [0,9792)
    float (*VshW)[65] = (float (*)[65])(smem + 9792 + 2340 * w);       // [9792,19152)
    float* GshW       = (float*)(smem + 19152 + 324 * w);              // [19152,20448)
    float* qdW        = (float*)(smem + 20448 + 48 * w);               // [20448,20640)
    float (*PWW)[4]   = (float (*)[4])(smem + 20640 + 576 * w);        // [20640,22944)

    const float* qp    = qh + (size_t)(bh * Tn + i) * HS;
    const float* kbase = kh + (size_t)bh * Tn * HS;
    const float* vbase = vh + (size_t)bh * Tn * HS;

    // q_i resident in registers for the whole sim phase
    float4 qv[16];
    #pragma unroll
    for (int t = 0; t < 16; ++t) qv[t] = ((const float4*)qp)[t];

    float sv[8];
    #pragma unroll
    for (int r = 0; r < 8; ++r) sv[r] = -INFINITY;

    const int cmax = (i0 + 3) >> 6;    // block-uniform
    const int rmax = i >> 6;

    // software-pipelined chunk staging: prefetch chunk c+1 while computing chunk c
    float4 pre[4];
    {
        const float4* src = (const float4*)kbase;
        #pragma unroll
        for (int u = 0; u < 4; ++u) pre[u] = src[threadIdx.x + u * 256];
    }
    #pragma unroll
    for (int c = 0; c < 8; ++c) {
        if (c <= cmax) {
            #pragma unroll
            for (int u = 0; u < 4; ++u) {
                int e = threadIdx.x + u * 256;
                *(float4*)&Klds[e >> 4][(e & 15) * 4] = pre[u];
            }
            __syncthreads();
            if (c + 1 <= cmax) {
                const float4* src = (const float4*)(kbase + (size_t)(c + 1) * 64 * HS);
                #pragma unroll
                for (int u = 0; u < 4; ++u) pre[u] = src[threadIdx.x + u * 256];
            }
            if (c <= rmax) {
                const int j = c * 64 + lane;
                const float4* kr = (const float4*)&Klds[lane][0];
                float acc = 0.f;
                #pragma unroll
                for (int t = 0; t < 16; ++t) {
                    float4 kv = kr[t];
                    acc += kv.x * qv[t].x; acc += kv.y * qv[t].y;
                    acc += kv.z * qv[t].z; acc += kv.w * qv[t].w;
                }
                sv[c] = (j <= i) ? acc : -INFINITY;
            }
            __syncthreads();   // last barrier in the kernel: after this, Klds is dead
        }
    }

    // qd0 = sim[i] = k_i . q_i
    float qd0 = 0.f;
    #pragma unroll
    for (int c = 0; c < 8; ++c) {
        float t = __shfl(sv[c], i & 63, 64);
        if (c == rmax) qd0 = t;
    }

    // top-8: 8 in-register butterfly argmax passes (value desc, tie -> lower index)
    float topv[8]; int topi[8];
    #pragma unroll
    for (int p = 0; p < MTOP; ++p) {
        float bv = -INFINITY; int bi = 0x7fffffff;
        #pragma unroll
        for (int r = 0; r < 8; ++r) {
            int j = r * 64 + lane;
            float v = sv[r];
            if (v > bv || (v == bv && j < bi)) { bv = v; bi = j; }
        }
        #pragma unroll
        for (int off = 32; off > 0; off >>= 1) {
            float ov = __shfl_xor(bv, off, 64);
            int   oi = __shfl_xor(bi, off, 64);
            if (ov > bv || (ov == bv && oi < bi)) { bv = ov; bi = oi; }
        }
        topv[p] = bv; topi[p] = bi;
        const int rs = bi >> 6, ls = bi & 63;
        #pragma unroll
        for (int r = 0; r < 8; ++r)
            if (r == rs && lane == ls) sv[r] = -INFINITY;
    }

    // validity bitmask per slot (wave-uniform)
    const int n_cand = (i + 1 < MTOP) ? (i + 1) : MTOP;
    int vmask = 0;
    #pragma unroll
    for (int s = 0; s < MTOP; ++s)
        if (s < n_cand && topi[s] != i) vmask |= (1 << s);

    // stage selected K/V rows {i} U top_idx into per-wave LDS (coalesced, lane = d)
    #pragma unroll
    for (int a = 0; a < 9; ++a) {
        int t = (a == 0) ? i : topi[a - 1];
        KshW[a][lane] = kbase[(size_t)t * HS + lane];
        VshW[a][lane] = vbase[(size_t)t * HS + lane];
    }
    if (lane < 9) {
        float val = qd0;
        #pragma unroll
        for (int p = 0; p < 8; ++p) if (lane == p + 1) val = topv[p];
        qdW[lane] = val;
    }

    // gram: lane l < 45 computes pair (PA[l], PB[l])  (per-wave LDS, no barrier needed)
    if (lane < 45) {
        const int a = PA[lane], b = PB[lane];
        const float4* rka = (const float4*)&KshW[a][0];
        const float4* rkb = (const float4*)&KshW[b][0];
        float acc = 0.f;
        #pragma unroll
        for (int t = 0; t < 16; ++t) {
            float4 fa = rka[t], fb = rkb[t];
            acc += fa.x * fb.x; acc += fa.y * fb.y;
            acc += fa.z * fb.z; acc += fa.w * fb.w;
        }
        GshW[a * 9 + b] = acc;
        GshW[b * 9 + a] = acc;
    }

    // combos on lanes 0..35
    float score = -INFINITY;
    int ca = 0, cb = 0, sdim = 1;
    if (lane < NCOMB) {
        const int sl0 = C_SL0[lane], sl1 = C_SL1[lane];
        sdim = (sl1 < 0) ? 1 : 2;
        ca = sl0 + 1;
        cb = (sl1 < 0) ? 0 : sl1 + 1;
        bool valid = ((vmask >> sl0) & 1);
        if (sdim == 2) valid = valid && ((vmask >> sl1) & 1);
        float G00 = GshW[0];
        float Gaa = GshW[ca * 9 + ca];
        float G0a = GshW[ca];
        float det;
        if (sdim == 1) {
            det = G00 * Gaa - G0a * G0a;
        } else {
            float G0b = GshW[cb];
            float Gab = GshW[ca * 9 + cb];
            float Gbb = GshW[cb * 9 + cb];
            det = G00 * (Gaa * Gbb - Gab * Gab)
                - G0a * (G0a * Gbb - Gab * G0b)
                + G0b * (G0a * Gab - Gaa * G0b);
        }
        score = valid ? (logf(det + 1e-6f) / (float)(sdim + 1)) : NEGV;
    }
    // softmax over scores via butterfly (lanes>=36 contribute -inf / 0)
    float mx = score;
    #pragma unroll
    for (int off = 32; off > 0; off >>= 1) mx = fmaxf(mx, __shfl_xor(mx, off, 64));
    float e = (lane < NCOMB) ? expf(score - mx) : 0.f;
    float sum = e;
    #pragma unroll
    for (int off = 32; off > 0; off >>= 1) sum += __shfl_xor(sum, off, 64);
    const bool hasValid = (mx > -1e29f);

    if (lane < NCOMB) {
        float prob = e / sum;
        float d0 = qdW[0]  * 0.125f;
        float d1 = qdW[ca] * 0.125f;
        float d2 = (sdim == 2) ? qdW[cb] * 0.125f : -INFINITY;
        float m2 = fmaxf(fmaxf(d0, d1), d2);
        float e0 = expf(d0 - m2), e1 = expf(d1 - m2);
        float e2 = (sdim == 2) ? expf(d2 - m2) : 0.f;
        float inv = prob / (e0 + e1 + e2);
        float4 pw = {e0 * inv, e1 * inv, e2 * inv, 0.f};
        *(float4*)&PWW[lane][0] = pw;
    }

    // y[d], d = lane (per-wave LDS reads; in-wave ordering only)
    const float v0 = VshW[0][lane];
    float y;
    if (!hasValid) {
        y = v0;
    } else {
        float acc = 0.f;
        #pragma unroll
        for (int c = 0; c < NCOMB; ++c) {
            float4 pw = *(const float4*)&PWW[c][0];
            int a = C_SL0[c] + 1;
            int b = (C_SL1[c] < 0) ? 0 : C_SL1[c] + 1;   // pw.z == 0 when sdim==1
            acc += pw.x * v0 + pw.y * VshW[a][lane] + pw.z * VshW[b][lane];
        }
        y = acc;
    }
    const int bb = bh / Hn, h = bh % Hn;
    yb[((size_t)(bb * Tn + i)) * Cn + h * HS + lane] = bf_rne(y);
}

extern "C" void kernel_launch(void* const* d_in, const int* in_sizes, int n_in,
                              void* d_out, int out_size, void* d_ws, size_t ws_size,
                              hipStream_t stream) {
    const float* x      = (const float*)d_in[0];
    const float* W_attn = (const float*)d_in[1];
    const float* b_attn = (const float*)d_in[2];
    const float* W_proj = (const float*)d_in[3];
    const float* b_proj = (const float*)d_in[4];
    float* out = (float*)d_out;

    char* ws = (char*)d_ws;
    float* qh = (float*)(ws);                              // 3 MB
    float* kh = (float*)(ws + 3145728);                    // 3 MB
    float* vh = (float*)(ws + 6291456);                    // 3 MB
    unsigned short* xhi = (unsigned short*)(ws + 9437184); // 1.5 MB
    unsigned short* xlo = (unsigned short*)(ws + 11010048);// 1.5 MB
    unsigned short* Whi = (unsigned short*)(ws + 12582912);// 3.375 MB
    unsigned short* Wlo = (unsigned short*)(ws + 16121856);// 3.375 MB -> 18.75 MB total
    unsigned short* ybf  = xhi;  // xhi dead after mfma_qkv
    unsigned short* Wpbf = xlo;  // xlo dead after mfma_qkv

    const int NX = Bn * Tn * Cn;   // 786432
    const int NW = 3 * Cn * Cn;    // 1769472
    const int NP = Cn * Cn;        // 589824

    // 1) split-convert x and W_attn to bf16 hi/lo
    conv_split<<<dim3((NX + 255) / 256), 256, 0, stream>>>(x, xhi, xlo, NX);
    conv_split<<<dim3((NW + 255) / 256), 256, 0, stream>>>(W_attn, Whi, Wlo, NW);

    // 2) qkv = x @ W_attn^T + b via 3-term split-bf16 MFMA, scatter to per-head fp32
    mfma_qkv<<<dim3(36, 16), 256, 0, stream>>>(xhi, xlo, Whi, Wlo, b_attn, qh, kh, vh);

    // 3) convert W_proj to bf16 (into xlo region, now dead)
    conv_bf<<<dim3((NP + 255) / 256), 256, 0, stream>>>(W_proj, Wpbf, NP);

    // 4) dpp: one wave per (head, token); writes y bf16 into xhi region (now dead)
    dpp_kernel<<<dim3(BH, Tn / 4), 256, 0, stream>>>(qh, kh, vh, ybf);

    // 5) out = y @ Wp^T + bp via bf16 MFMA
    mfma_proj<<<dim3(12, 16), 256, 0, stream>>>(ybf, Wpbf, b_proj, out, Bn * Tn, Cn, Cn);
}

// Round 8
// 211.788 us; speedup vs baseline: 1.3331x; 1.1378x over previous
//
#include <hip/hip_runtime.h>
#include <math.h>

#define Bn 2
#define Hn 12
#define Tn 512
#define Cn 768
#define HS 64
#define BH 24
#define MTOP 8
#define NCOMB 36
#define NEGV -1e30f

typedef __bf16 bf16x8 __attribute__((ext_vector_type(8)));
typedef float f32x4 __attribute__((ext_vector_type(4)));

// combo tables: slots (0..7) for size-1 (8 combos) then size-2 (28 combos), lexicographic
__device__ __constant__ int C_SL0[NCOMB] = {
  0,1,2,3,4,5,6,7,
  0,0,0,0,0,0,0,
  1,1,1,1,1,1,
  2,2,2,2,2,
  3,3,3,3,
  4,4,4,
  5,5,
  6};
__device__ __constant__ int C_SL1[NCOMB] = {
  -1,-1,-1,-1,-1,-1,-1,-1,
  1,2,3,4,5,6,7,
  2,3,4,5,6,7,
  3,4,5,6,7,
  4,5,6,7,
  5,6,7,
  6,7,
  7};

// gram pair tables: 45 pairs (a<=b) over 9 tokens
__device__ __constant__ int PA[45] = {
  0,0,0,0,0,0,0,0,0,
  1,1,1,1,1,1,1,1,
  2,2,2,2,2,2,2,
  3,3,3,3,3,3,
  4,4,4,4,4,
  5,5,5,5,
  6,6,6,
  7,7,
  8};
__device__ __constant__ int PB[45] = {
  0,1,2,3,4,5,6,7,8,
  1,2,3,4,5,6,7,8,
  2,3,4,5,6,7,8,
  3,4,5,6,7,8,
  4,5,6,7,8,
  5,6,7,8,
  6,7,8,
  7,8,
  8};

// lower-triangle 8x8 tile enumeration for the causal S kernel
__device__ __constant__ int TI[36] = {
  0,1,1,2,2,2,3,3,3,3,4,4,4,4,4,5,5,5,5,5,5,6,6,6,6,6,6,6,7,7,7,7,7,7,7,7};
__device__ __constant__ int TJ[36] = {
  0,0,1,0,1,2,0,1,2,3,0,1,2,3,4,0,1,2,3,4,5,0,1,2,3,4,5,6,0,1,2,3,4,5,6,7};

__device__ __forceinline__ unsigned short bf_rne(float x) {
    unsigned u = __float_as_uint(x);
    return (unsigned short)((u + 0x7fff + ((u >> 16) & 1)) >> 16);
}
__device__ __forceinline__ float bf_f(unsigned short s) {
    return __uint_as_float(((unsigned)s) << 16);
}

// ---------------- fp32 -> (bf16 hi, bf16 lo) split ------------------------------------
__global__ __launch_bounds__(256) void conv_split(const float* __restrict__ s,
                                                  unsigned short* __restrict__ hi,
                                                  unsigned short* __restrict__ lo, int n) {
    int idx = blockIdx.x * 256 + threadIdx.x;
    if (idx < n) {
        float x = s[idx];
        unsigned short h = bf_rne(x);
        hi[idx] = h;
        lo[idx] = bf_rne(x - bf_f(h));
    }
}

// ---------------- fp32 -> bf16 (RNE) --------------------------------------------------
__global__ __launch_bounds__(256) void conv_bf(const float* __restrict__ s,
                                               unsigned short* __restrict__ d, int n) {
    int idx = blockIdx.x * 256 + threadIdx.x;
    if (idx < n) d[idx] = bf_rne(s[idx]);
}

// ---------------- 3-term split-bf16 MFMA qkv GEMM -------------------------------------
// C = (Ahi+Alo)@(Bhi+Blo)^T + bias, dropping lo*lo (error ~2^-18 rel ~ fp32 noise).
// Epilogue: q -> 3-way bf16 split (q1,q2,q3) for the MFMA sim kernel;
//           k -> fp32 kh (gram) + 3-way split (k1,k2,k3); v -> fp32 vh.
__global__ __launch_bounds__(256) void mfma_qkv(const unsigned short* __restrict__ Ahi,
                                                const unsigned short* __restrict__ Alo,
                                                const unsigned short* __restrict__ Bhi,
                                                const unsigned short* __restrict__ Blo,
                                                const float* __restrict__ bias,
                                                unsigned short* __restrict__ q1,
                                                unsigned short* __restrict__ q2,
                                                unsigned short* __restrict__ q3,
                                                unsigned short* __restrict__ k1,
                                                unsigned short* __restrict__ k2,
                                                unsigned short* __restrict__ k3,
                                                float* __restrict__ kh,
                                                float* __restrict__ vh) {
    const int wv = threadIdx.x >> 6;
    const int lane = threadIdx.x & 63;
    const int tn = blockIdx.x * 64;
    const int m0 = blockIdx.y * 64 + (wv >> 1) * 32;
    const int n0 = tn + (wv & 1) * 32;
    const int r = lane & 15;
    const int kq = lane >> 4;
    f32x4 acc[2][2] = {};
    const size_t ao0 = (size_t)(m0 + r) * Cn + kq * 8;
    const size_t ao1 = ao0 + 16 * Cn;
    const size_t bo0 = (size_t)(n0 + r) * Cn + kq * 8;
    const size_t bo1 = bo0 + 16 * Cn;
    for (int k = 0; k < Cn; k += 32) {
        bf16x8 a0h = *(const bf16x8*)(Ahi + ao0 + k);
        bf16x8 a1h = *(const bf16x8*)(Ahi + ao1 + k);
        bf16x8 a0l = *(const bf16x8*)(Alo + ao0 + k);
        bf16x8 a1l = *(const bf16x8*)(Alo + ao1 + k);
        bf16x8 b0h = *(const bf16x8*)(Bhi + bo0 + k);
        bf16x8 b1h = *(const bf16x8*)(Bhi + bo1 + k);
        bf16x8 b0l = *(const bf16x8*)(Blo + bo0 + k);
        bf16x8 b1l = *(const bf16x8*)(Blo + bo1 + k);
        acc[0][0] = __builtin_amdgcn_mfma_f32_16x16x32_bf16(a0h, b0h, acc[0][0], 0, 0, 0);
        acc[0][1] = __builtin_amdgcn_mfma_f32_16x16x32_bf16(a0h, b1h, acc[0][1], 0, 0, 0);
        acc[1][0] = __builtin_amdgcn_mfma_f32_16x16x32_bf16(a1h, b0h, acc[1][0], 0, 0, 0);
        acc[1][1] = __builtin_amdgcn_mfma_f32_16x16x32_bf16(a1h, b1h, acc[1][1], 0, 0, 0);
        acc[0][0] = __builtin_amdgcn_mfma_f32_16x16x32_bf16(a0h, b0l, acc[0][0], 0, 0, 0);
        acc[0][1] = __builtin_amdgcn_mfma_f32_16x16x32_bf16(a0h, b1l, acc[0][1], 0, 0, 0);
        acc[1][0] = __builtin_amdgcn_mfma_f32_16x16x32_bf16(a1h, b0l, acc[1][0], 0, 0, 0);
        acc[1][1] = __builtin_amdgcn_mfma_f32_16x16x32_bf16(a1h, b1l, acc[1][1], 0, 0, 0);
        acc[0][0] = __builtin_amdgcn_mfma_f32_16x16x32_bf16(a0l, b0h, acc[0][0], 0, 0, 0);
        acc[0][1] = __builtin_amdgcn_mfma_f32_16x16x32_bf16(a0l, b1h, acc[0][1], 0, 0, 0);
        acc[1][0] = __builtin_amdgcn_mfma_f32_16x16x32_bf16(a1l, b0h, acc[1][0], 0, 0, 0);
        acc[1][1] = __builtin_amdgcn_mfma_f32_16x16x32_bf16(a1l, b1h, acc[1][1], 0, 0, 0);
    }
    // D mapping: col = lane&15 (n), row = (lane>>4)*4 + rr (m)
    const int part = tn / Cn;                  // 0=q,1=k,2=v (64-tile never crosses parts)
    #pragma unroll
    for (int im = 0; im < 2; ++im) {
        #pragma unroll
        for (int in = 0; in < 2; ++in) {
            #pragma unroll
            for (int rr = 0; rr < 4; ++rr) {
                int mm = m0 + im * 16 + kq * 4 + rr;
                int nn = n0 + in * 16 + r;
                float val = acc[im][in][rr] + bias[nn];
                int bb = mm >> 9, t = mm & 511;
                int c = nn - part * Cn;
                int h = c >> 6, d = c & 63;
                size_t idx = ((size_t)((bb * Hn) + h) * Tn + t) * HS + d;
                if (part == 2) {
                    vh[idx] = val;
                } else {
                    // 3-way bf16 split: ~25 mantissa bits -> sim error < fp32 noise
                    unsigned short s1 = bf_rne(val);
                    float r1 = val - bf_f(s1);
                    unsigned short s2 = bf_rne(r1);
                    unsigned short s3 = bf_rne(r1 - bf_f(s2));
                    if (part == 0) {
                        q1[idx] = s1; q2[idx] = s2; q3[idx] = s3;
                    } else {
                        kh[idx] = val;
                        k1[idx] = s1; k2[idx] = s2; k3[idx] = s3;
                    }
                }
            }
        }
    }
}

// ---------------- causal sim matrix: S[bh] = Q @ K^T via 6-term split MFMA -------------
// 3-way split (q=q1+q2+q3), keep products down to 2^-17 magnitude:
// q1k1 + q1k2 + q2k1 + q1k3 + q3k1 + q2k2 -> residual ~2^-25 (below fp32 dot noise).
// Lower-triangle 64x64 tiles only (36 of 64 per head).
__global__ __launch_bounds__(256) void mfma_sim(const unsigned short* __restrict__ q1,
                                                const unsigned short* __restrict__ q2,
                                                const unsigned short* __restrict__ q3,
                                                const unsigned short* __restrict__ k1,
                                                const unsigned short* __restrict__ k2,
                                                const unsigned short* __restrict__ k3,
                                                float* __restrict__ S) {
    const int bh = blockIdx.y;
    const int ti = TI[blockIdx.x], tj = TJ[blockIdx.x];
    const int wv = threadIdx.x >> 6;
    const int lane = threadIdx.x & 63;
    const int m0 = ti * 64 + (wv >> 1) * 32;
    const int n0 = tj * 64 + (wv & 1) * 32;
    const int r = lane & 15;
    const int kq = lane >> 4;
    f32x4 acc[2][2] = {};
    const size_t ab = ((size_t)bh * Tn + m0 + r) * HS + kq * 8;
    const size_t bb = ((size_t)bh * Tn + n0 + r) * HS + kq * 8;
    #pragma unroll
    for (int k = 0; k < HS; k += 32) {
        bf16x8 a1[2], a2[2], a3[2], b1[2], b2[2], b3[2];
        #pragma unroll
        for (int hf = 0; hf < 2; ++hf) {
            size_t ao = ab + (size_t)hf * 16 * HS + k;
            size_t bo = bb + (size_t)hf * 16 * HS + k;
            a1[hf] = *(const bf16x8*)(q1 + ao);
            a2[hf] = *(const bf16x8*)(q2 + ao);
            a3[hf] = *(const bf16x8*)(q3 + ao);
            b1[hf] = *(const bf16x8*)(k1 + bo);
            b2[hf] = *(const bf16x8*)(k2 + bo);
            b3[hf] = *(const bf16x8*)(k3 + bo);
        }
        #pragma unroll
        for (int ih = 0; ih < 2; ++ih)
            #pragma unroll
            for (int jh = 0; jh < 2; ++jh) {
                acc[ih][jh] = __builtin_amdgcn_mfma_f32_16x16x32_bf16(a1[ih], b1[jh], acc[ih][jh], 0, 0, 0);
                acc[ih][jh] = __builtin_amdgcn_mfma_f32_16x16x32_bf16(a1[ih], b2[jh], acc[ih][jh], 0, 0, 0);
                acc[ih][jh] = __builtin_amdgcn_mfma_f32_16x16x32_bf16(a2[ih], b1[jh], acc[ih][jh], 0, 0, 0);
                acc[ih][jh] = __builtin_amdgcn_mfma_f32_16x16x32_bf16(a1[ih], b3[jh], acc[ih][jh], 0, 0, 0);
                acc[ih][jh] = __builtin_amdgcn_mfma_f32_16x16x32_bf16(a3[ih], b1[jh], acc[ih][jh], 0, 0, 0);
                acc[ih][jh] = __builtin_amdgcn_mfma_f32_16x16x32_bf16(a2[ih], b2[jh], acc[ih][jh], 0, 0, 0);
            }
    }
    float* Sb = S + (size_t)bh * Tn * Tn;
    #pragma unroll
    for (int ih = 0; ih < 2; ++ih)
        #pragma unroll
        for (int jh = 0; jh < 2; ++jh)
            #pragma unroll
            for (int rr = 0; rr < 4; ++rr) {
                int mm = m0 + ih * 16 + kq * 4 + rr;
                int nn = n0 + jh * 16 + r;
                Sb[(size_t)mm * Tn + nn] = acc[ih][jh][rr];
            }
}

// ---------------- bf16 MFMA GEMM (single-term): out = A @ B^T + bias, flat ------------
__global__ __launch_bounds__(256) void mfma_proj(const unsigned short* __restrict__ Abf,
                                                 const unsigned short* __restrict__ Bbf,
                                                 const float* __restrict__ bias,
                                                 float* __restrict__ outp,
                                                 int M, int N, int K) {
    const int wv = threadIdx.x >> 6;
    const int lane = threadIdx.x & 63;
    const int m0 = blockIdx.y * 64 + (wv >> 1) * 32;
    const int n0 = blockIdx.x * 64 + (wv & 1) * 32;
    const int r = lane & 15;
    const int kq = lane >> 4;
    f32x4 acc[2][2] = {};
    const unsigned short* arow0 = Abf + (size_t)(m0 + r) * K + kq * 8;
    const unsigned short* arow1 = arow0 + 16 * K;
    const unsigned short* brow0 = Bbf + (size_t)(n0 + r) * K + kq * 8;
    const unsigned short* brow1 = brow0 + 16 * K;
    for (int k = 0; k < K; k += 32) {
        bf16x8 a0 = *(const bf16x8*)(arow0 + k);
        bf16x8 a1 = *(const bf16x8*)(arow1 + k);
        bf16x8 b0 = *(const bf16x8*)(brow0 + k);
        bf16x8 b1 = *(const bf16x8*)(brow1 + k);
        acc[0][0] = __builtin_amdgcn_mfma_f32_16x16x32_bf16(a0, b0, acc[0][0], 0, 0, 0);
        acc[0][1] = __builtin_amdgcn_mfma_f32_16x16x32_bf16(a0, b1, acc[0][1], 0, 0, 0);
        acc[1][0] = __builtin_amdgcn_mfma_f32_16x16x32_bf16(a1, b0, acc[1][0], 0, 0, 0);
        acc[1][1] = __builtin_amdgcn_mfma_f32_16x16x32_bf16(a1, b1, acc[1][1], 0, 0, 0);
    }
    #pragma unroll
    for (int im = 0; im < 2; ++im)
        #pragma unroll
        for (int in = 0; in < 2; ++in)
            #pragma unroll
            for (int rr = 0; rr < 4; ++rr) {
                int mm = m0 + im * 16 + kq * 4 + rr;
                int nn = n0 + in * 16 + r;
                outp[(size_t)mm * N + nn] = acc[im][in][rr] + bias[nn];
            }
}

// ---------------- DPP selection: one WAVE per token, barrier-free ---------------------
// sim row read directly from the precomputed S matrix (coalesced); per-wave-private
// LDS tail; NO __syncthreads anywhere. No min-waves bound (r6: spill disaster).
__global__ __launch_bounds__(256) void dpp_kernel(const float* __restrict__ S,
                                                  const float* __restrict__ kh,
                                                  const float* __restrict__ vh,
                                                  unsigned short* __restrict__ yb) {
    const int bh = blockIdx.x;
    const int w = threadIdx.x >> 6;
    const int lane = threadIdx.x & 63;
    const int i = blockIdx.y * 4 + w;

    __shared__ __align__(16) char smem[22944];
    float (*KshW)[68] = (float (*)[68])(smem + 2448 * w);              // [0,9792)
    float (*VshW)[65] = (float (*)[65])(smem + 9792 + 2340 * w);       // [9792,19152)
    float* GshW       = (float*)(smem + 19152 + 324 * w);              // [19152,20448)
    float* qdW        = (float*)(smem + 20448 + 48 * w);               // [20448,20640)
    float (*PWW)[4]   = (float (*)[4])(smem + 20640 + 576 * w);        // [20640,22944)

    const float* sp    = S + ((size_t)bh * Tn + i) * Tn;
    const float* kbase = kh + (size_t)bh * Tn * HS;
    const float* vbase = vh + (size_t)bh * Tn * HS;

    const int rmax = i >> 6;
    float sv[8];
    #pragma unroll
    for (int rr = 0; rr < 8; ++rr) {
        sv[rr] = -INFINITY;
        if (rr <= rmax) {
            int j = rr * 64 + lane;
            float s = sp[j];                    // coalesced fp32 row read
            sv[rr] = (j <= i) ? s : -INFINITY;  // diagonal tile is fully computed
        }
    }

    // qd0 = sim[i][i]
    float qd0 = 0.f;
    #pragma unroll
    for (int c = 0; c < 8; ++c) {
        float t = __shfl(sv[c], i & 63, 64);
        if (c == rmax) qd0 = t;
    }

    // top-8: 8 in-register butterfly argmax passes (value desc, tie -> lower index)
    float topv[8]; int topi[8];
    #pragma unroll
    for (int p = 0; p < MTOP; ++p) {
        float bv = -INFINITY; int bi = 0x7fffffff;
        #pragma unroll
        for (int r = 0; r < 8; ++r) {
            int j = r * 64 + lane;
            float v = sv[r];
            if (v > bv || (v == bv && j < bi)) { bv = v; bi = j; }
        }
        #pragma unroll
        for (int off = 32; off > 0; off >>= 1) {
            float ov = __shfl_xor(bv, off, 64);
            int   oi = __shfl_xor(bi, off, 64);
            if (ov > bv || (ov == bv && oi < bi)) { bv = ov; bi = oi; }
        }
        topv[p] = bv; topi[p] = bi;
        const int rs = bi >> 6, ls = bi & 63;
        #pragma unroll
        for (int r = 0; r < 8; ++r)
            if (r == rs && lane == ls) sv[r] = -INFINITY;
    }

    // validity bitmask per slot (wave-uniform)
    const int n_cand = (i + 1 < MTOP) ? (i + 1) : MTOP;
    int vmask = 0;
    #pragma unroll
    for (int s = 0; s < MTOP; ++s)
        if (s < n_cand && topi[s] != i) vmask |= (1 << s);

    // stage selected K/V rows {i} U top_idx into per-wave LDS (coalesced, lane = d)
    #pragma unroll
    for (int a = 0; a < 9; ++a) {
        int t = (a == 0) ? i : topi[a - 1];
        KshW[a][lane] = kbase[(size_t)t * HS + lane];
        VshW[a][lane] = vbase[(size_t)t * HS + lane];
    }
    if (lane < 9) {
        float val = qd0;
        #pragma unroll
        for (int p = 0; p < 8; ++p) if (lane == p + 1) val = topv[p];
        qdW[lane] = val;
    }

    // gram: lane l < 45 computes pair (PA[l], PB[l])  (per-wave LDS, no barrier)
    if (lane < 45) {
        const int a = PA[lane], b = PB[lane];
        const float4* rka = (const float4*)&KshW[a][0];
        const float4* rkb = (const float4*)&KshW[b][0];
        float acc = 0.f;
        #pragma unroll
        for (int t = 0; t < 16; ++t) {
            float4 fa = rka[t], fb = rkb[t];
            acc += fa.x * fb.x; acc += fa.y * fb.y;
            acc += fa.z * fb.z; acc += fa.w * fb.w;
        }
        GshW[a * 9 + b] = acc;
        GshW[b * 9 + a] = acc;
    }

    // combos on lanes 0..35
    float score = -INFINITY;
    int ca = 0, cb = 0, sdim = 1;
    if (lane < NCOMB) {
        const int sl0 = C_SL0[lane], sl1 = C_SL1[lane];
        sdim = (sl1 < 0) ? 1 : 2;
        ca = sl0 + 1;
        cb = (sl1 < 0) ? 0 : sl1 + 1;
        bool valid = ((vmask >> sl0) & 1);
        if (sdim == 2) valid = valid && ((vmask >> sl1) & 1);
        float G00 = GshW[0];
        float Gaa = GshW[ca * 9 + ca];
        float G0a = GshW[ca];
        float det;
        if (sdim == 1) {
            det = G00 * Gaa - G0a * G0a;
        } else {
            float G0b = GshW[cb];
            float Gab = GshW[ca * 9 + cb];
            float Gbb = GshW[cb * 9 + cb];
            det = G00 * (Gaa * Gbb - Gab * Gab)
                - G0a * (G0a * Gbb - Gab * G0b)
                + G0b * (G0a * Gab - Gaa * G0b);
        }
        score = valid ? (logf(det + 1e-6f) / (float)(sdim + 1)) : NEGV;
    }
    // softmax over scores via butterfly (lanes>=36 contribute -inf / 0)
    float mx = score;
    #pragma unroll
    for (int off = 32; off > 0; off >>= 1) mx = fmaxf(mx, __shfl_xor(mx, off, 64));
    float e = (lane < NCOMB) ? expf(score - mx) : 0.f;
    float sum = e;
    #pragma unroll
    for (int off = 32; off > 0; off >>= 1) sum += __shfl_xor(sum, off, 64);
    const bool hasValid = (mx > -1e29f);

    if (lane < NCOMB) {
        float prob = e / sum;
        float d0 = qdW[0]  * 0.125f;
        float d1 = qdW[ca] * 0.125f;
        float d2 = (sdim == 2) ? qdW[cb] * 0.125f : -INFINITY;
        float m2 = fmaxf(fmaxf(d0, d1), d2);
        float e0 = expf(d0 - m2), e1 = expf(d1 - m2);
        float e2 = (sdim == 2) ? expf(d2 - m2) : 0.f;
        float inv = prob / (e0 + e1 + e2);
        float4 pw = {e0 * inv, e1 * inv, e2 * inv, 0.f};
        *(float4*)&PWW[lane][0] = pw;
    }

    // y[d], d = lane (per-wave LDS reads; in-wave ordering only)
    const float v0 = VshW[0][lane];
    float y;
    if (!hasValid) {
        y = v0;
    } else {
        float acc = 0.f;
        #pragma unroll
        for (int c = 0; c < NCOMB; ++c) {
            float4 pw = *(const float4*)&PWW[c][0];
            int a = C_SL0[c] + 1;
            int b = (C_SL1[c] < 0) ? 0 : C_SL1[c] + 1;   // pw.z == 0 when sdim==1
            acc += pw.x * v0 + pw.y * VshW[a][lane] + pw.z * VshW[b][lane];
        }
        y = acc;
    }
    const int bb = bh / Hn, h = bh % Hn;
    yb[((size_t)(bb * Tn + i)) * Cn + h * HS + lane] = bf_rne(y);
}

extern "C" void kernel_launch(void* const* d_in, const int* in_sizes, int n_in,
                              void* d_out, int out_size, void* d_ws, size_t ws_size,
                              hipStream_t stream) {
    const float* x      = (const float*)d_in[0];
    const float* W_attn = (const float*)d_in[1];
    const float* b_attn = (const float*)d_in[2];
    const float* W_proj = (const float*)d_in[3];
    const float* b_proj = (const float*)d_in[4];
    float* out = (float*)d_out;

    char* ws = (char*)d_ws;
    // layout (bytes); Whi/Wlo overlay the S region (dead before mfma_sim writes S)
    float* kh = (float*)(ws);                                   //  0.0 MB, 3 MB
    float* vh = (float*)(ws + 3145728);                         //  3.0 MB, 3 MB
    unsigned short* q1 = (unsigned short*)(ws + 6291456);       //  6.0 MB, 1.5 MB each
    unsigned short* q2 = (unsigned short*)(ws + 7864320);
    unsigned short* q3 = (unsigned short*)(ws + 9437184);
    unsigned short* k1 = (unsigned short*)(ws + 11010048);
    unsigned short* k2 = (unsigned short*)(ws + 12582912);
    unsigned short* k3 = (unsigned short*)(ws + 14155776);
    unsigned short* xhi = (unsigned short*)(ws + 15728640);     // 15.0 MB, 1.5 MB
    unsigned short* xlo = (unsigned short*)(ws + 17301504);     // 16.5 MB, 1.5 MB
    float* S = (float*)(ws + 18874368);                         // 18.0 MB, 24 MB -> 42 MB
    unsigned short* Whi = (unsigned short*)(ws + 18874368);     // overlay in S region
    unsigned short* Wlo = (unsigned short*)(ws + 22413312);
    unsigned short* ybf  = xhi;  // xhi dead after mfma_qkv
    unsigned short* Wpbf = xlo;  // xlo dead after mfma_qkv

    const int NX = Bn * Tn * Cn;   // 786432
    const int NW = 3 * Cn * Cn;    // 1769472
    const int NP = Cn * Cn;        // 589824

    // 1) split-convert x and W_attn to bf16 hi/lo
    conv_split<<<dim3((NX + 255) / 256), 256, 0, stream>>>(x, xhi, xlo, NX);
    conv_split<<<dim3((NW + 255) / 256), 256, 0, stream>>>(W_attn, Whi, Wlo, NW);

    // 2) qkv via 3-term split-bf16 MFMA; q/k re-split 3-way bf16, k/v also fp32
    mfma_qkv<<<dim3(36, 16), 256, 0, stream>>>(xhi, xlo, Whi, Wlo, b_attn,
                                               q1, q2, q3, k1, k2, k3, kh, vh);

    // 3) causal sim matrix S = Q @ K^T (6-term 3-way split, lower-triangle tiles)
    mfma_sim<<<dim3(36, BH), 256, 0, stream>>>(q1, q2, q3, k1, k2, k3, S);

    // 4) convert W_proj to bf16 (into xlo region, now dead)
    conv_bf<<<dim3((NP + 255) / 256), 256, 0, stream>>>(W_proj, Wpbf, NP);

    // 5) dpp: one wave per (head, token), barrier-free, reads S rows
    dpp_kernel<<<dim3(BH, Tn / 4), 256, 0, stream>>>(S, kh, vh, ybf);

    // 6) out = y @ Wp^T + bp via bf16 MFMA
    mfma_proj<<<dim3(12, 16), 256, 0, stream>>>(ybf, Wpbf, b_proj, out, Bn * Tn, Cn, Cn);
}

// Round 9
// 183.898 us; speedup vs baseline: 1.5353x; 1.1517x over previous
//
#include <hip/hip_runtime.h>
#include <math.h>

#define Bn 2
#define Hn 12
#define Tn 512
#define Cn 768
#define HS 64
#define BH 24
#define MTOP 8
#define NCOMB 36
#define NEGV -1e30f

typedef __bf16 bf16x8 __attribute__((ext_vector_type(8)));
typedef float f32x4 __attribute__((ext_vector_type(4)));

__device__ __constant__ int C_SL0[NCOMB] = {
  0,1,2,3,4,5,6,7,
  0,0,0,0,0,0,0,
  1,1,1,1,1,1,
  2,2,2,2,2,
  3,3,3,3,
  4,4,4,
  5,5,
  6};
__device__ __constant__ int C_SL1[NCOMB] = {
  -1,-1,-1,-1,-1,-1,-1,-1,
  1,2,3,4,5,6,7,
  2,3,4,5,6,7,
  3,4,5,6,7,
  4,5,6,7,
  5,6,7,
  6,7,
  7};

__device__ __constant__ int PA[45] = {
  0,0,0,0,0,0,0,0,0,
  1,1,1,1,1,1,1,1,
  2,2,2,2,2,2,2,
  3,3,3,3,3,3,
  4,4,4,4,4,
  5,5,5,5,
  6,6,6,
  7,7,
  8};
__device__ __constant__ int PB[45] = {
  0,1,2,3,4,5,6,7,8,
  1,2,3,4,5,6,7,8,
  2,3,4,5,6,7,8,
  3,4,5,6,7,8,
  4,5,6,7,8,
  5,6,7,8,
  6,7,8,
  7,8,
  8};

// lower-triangle 8x8 tile enumeration (ti >= tj)
__device__ __constant__ int TI[36] = {
  0,1,1,2,2,2,3,3,3,3,4,4,4,4,4,5,5,5,5,5,5,6,6,6,6,6,6,6,7,7,7,7,7,7,7,7};
__device__ __constant__ int TJ[36] = {
  0,0,1,0,1,2,0,1,2,3,0,1,2,3,4,0,1,2,3,4,5,0,1,2,3,4,5,6,0,1,2,3,4,5,6,7};

__device__ __forceinline__ unsigned short bf_rne(float x) {
    unsigned u = __float_as_uint(x);
    return (unsigned short)((u + 0x7fff + ((u >> 16) & 1)) >> 16);
}
__device__ __forceinline__ float bf_f(unsigned short s) {
    return __uint_as_float(((unsigned)s) << 16);
}

// ---- fp32 -> concatenated hi/hi/lo bf16 layout (row stride 2304) ---------------------
// dst[r][c]=hi, dst[r][c+hiOff2]=hi, dst[r][c+loOff]=lo   (c in [0,768))
__global__ __launch_bounds__(256) void conv_cat(const float* __restrict__ s,
                                                unsigned short* __restrict__ dst,
                                                int n, int hiOff2, int loOff) {
    int idx = blockIdx.x * 256 + threadIdx.x;
    if (idx < n) {
        int r = idx / Cn, c = idx - r * Cn;
        float x = s[idx];
        unsigned short h = bf_rne(x);
        unsigned short l = bf_rne(x - bf_f(h));
        size_t base = (size_t)r * 2304 + c;
        dst[base] = h;
        dst[base + hiOff2] = h;
        dst[base + loOff] = l;
    }
}

__global__ __launch_bounds__(256) void conv_bf(const float* __restrict__ s,
                                               unsigned short* __restrict__ d, int n) {
    int idx = blockIdx.x * 256 + threadIdx.x;
    if (idx < n) d[idx] = bf_rne(s[idx]);
}

// ---- shared LDS-staged double-buffered bf16 NT GEMM core -----------------------------
// Block: 256 thr (4 waves, 2x2), tile 64x64, BK=64. Ag/Bg point at the tile's first
// row (row-major, stride K elems). One barrier per slab; register->LDS prefetch.
// acc[mi][ni]: out row = (wv>>1)*32 + mi*16 + (lane>>4)*4 + rr, col = (wv&1)*32 + ni*16 + (lane&15).
__device__ __forceinline__ void gemm_core(const unsigned short* __restrict__ Ag,
                                          const unsigned short* __restrict__ Bg,
                                          int K, int NS,
                                          unsigned short* Ab, unsigned short* Bb,
                                          f32x4 acc[2][2]) {
    const int tid = threadIdx.x;
    const int wv = tid >> 6, lane = tid & 63;
    const int r0 = tid >> 3;           // staging row 0..31 (and +32)
    const int c8 = (tid & 7) * 8;      // staging col chunk
    const int m0w = (wv >> 1) * 32;
    const int n0w = (wv & 1) * 32;
    const int fr = lane & 15;
    const int fk = (lane >> 4) * 8;

    const unsigned short* pa0 = Ag + (size_t)r0 * K + c8;
    const unsigned short* pa1 = Ag + (size_t)(r0 + 32) * K + c8;
    const unsigned short* pb0 = Bg + (size_t)r0 * K + c8;
    const unsigned short* pb1 = Bg + (size_t)(r0 + 32) * K + c8;

    bf16x8 ra0 = *(const bf16x8*)pa0;
    bf16x8 ra1 = *(const bf16x8*)pa1;
    bf16x8 rb0 = *(const bf16x8*)pb0;
    bf16x8 rb1 = *(const bf16x8*)pb1;

    const int sO = r0 * 72 + c8;       // LDS elem offset (row stride 72)
    for (int s = 0; s < NS; ++s) {
        const int bufo = (s & 1) * 4608;   // 64*72
        *(bf16x8*)(Ab + bufo + sO) = ra0;
        *(bf16x8*)(Ab + bufo + sO + 32 * 72) = ra1;
        *(bf16x8*)(Bb + bufo + sO) = rb0;
        *(bf16x8*)(Bb + bufo + sO + 32 * 72) = rb1;
        __syncthreads();
        if (s + 1 < NS) {                   // prefetch next slab while computing this one
            ra0 = *(const bf16x8*)(pa0 + (s + 1) * 64);
            ra1 = *(const bf16x8*)(pa1 + (s + 1) * 64);
            rb0 = *(const bf16x8*)(pb0 + (s + 1) * 64);
            rb1 = *(const bf16x8*)(pb1 + (s + 1) * 64);
        }
        #pragma unroll
        for (int ks = 0; ks < 2; ++ks) {
            bf16x8 af[2], bg[2];
            #pragma unroll
            for (int mi = 0; mi < 2; ++mi)
                af[mi] = *(const bf16x8*)(Ab + bufo + (m0w + 16 * mi + fr) * 72 + ks * 32 + fk);
            #pragma unroll
            for (int ni = 0; ni < 2; ++ni)
                bg[ni] = *(const bf16x8*)(Bb + bufo + (n0w + 16 * ni + fr) * 72 + ks * 32 + fk);
            #pragma unroll
            for (int mi = 0; mi < 2; ++mi)
                #pragma unroll
                for (int ni = 0; ni < 2; ++ni)
                    acc[mi][ni] = __builtin_amdgcn_mfma_f32_16x16x32_bf16(af[mi], bg[ni], acc[mi][ni], 0, 0, 0);
        }
        // NOTE: no second barrier needed — next iter stores to the OTHER buffer, and
        // its last readers were separated by the barrier above (double-buffer).
    }
}

// ---- qkv: C = xcat @ Wcat^T + bias (K'=2304 = 3-term split GEMM) ---------------------
// Epilogue scatters: q -> qcat 3-way-split dup layout; k -> kcat; v -> vh fp32.
__global__ __launch_bounds__(256) void mfma_qkv(const unsigned short* __restrict__ xcat,
                                                const unsigned short* __restrict__ Wcat,
                                                const float* __restrict__ bias,
                                                unsigned short* __restrict__ qcat,
                                                unsigned short* __restrict__ kcat,
                                                float* __restrict__ vh) {
    __shared__ unsigned short Ab[2 * 64 * 72];
    __shared__ unsigned short Bb[2 * 64 * 72];
    const int tm = blockIdx.x * 64;    // m fast -> same-n blocks spread across XCDs
    const int tn = blockIdx.y * 64;
    f32x4 acc[2][2] = {};
    gemm_core(xcat + (size_t)tm * 2304, Wcat + (size_t)tn * 2304, 2304, 36, Ab, Bb, acc);

    const int wv = threadIdx.x >> 6, lane = threadIdx.x & 63;
    const int kq = lane >> 4, r = lane & 15;
    const int part = tn / Cn;          // 0=q,1=k,2=v
    #pragma unroll
    for (int mi = 0; mi < 2; ++mi) {
        #pragma unroll
        for (int ni = 0; ni < 2; ++ni) {
            #pragma unroll
            for (int rr = 0; rr < 4; ++rr) {
                int mm = tm + (wv >> 1) * 32 + mi * 16 + kq * 4 + rr;
                int nn = tn + (wv & 1) * 32 + ni * 16 + r;
                float val = acc[mi][ni][rr] + bias[nn];
                int bb = mm >> 9, t = mm & 511;
                int c = nn - part * Cn;
                int h = c >> 6, d = c & 63;
                int bh = bb * Hn + h;
                if (part == 2) {
                    vh[((size_t)bh * Tn + t) * HS + d] = val;
                } else {
                    unsigned short s1 = bf_rne(val);
                    float r1 = val - bf_f(s1);
                    unsigned short s2 = bf_rne(r1);
                    unsigned short s3 = bf_rne(r1 - bf_f(s2));
                    size_t base = ((size_t)bh * Tn + t) * 384 + d;
                    if (part == 0) {   // qcat = [q1|q1|q2|q1|q3|q2]
                        qcat[base]       = s1;
                        qcat[base + 64]  = s1;
                        qcat[base + 192] = s1;
                        qcat[base + 128] = s2;
                        qcat[base + 320] = s2;
                        qcat[base + 256] = s3;
                    } else {           // kcat = [k1|k2|k1|k3|k1|k2]
                        kcat[base]       = s1;
                        kcat[base + 128] = s1;
                        kcat[base + 256] = s1;
                        kcat[base + 64]  = s2;
                        kcat[base + 320] = s2;
                        kcat[base + 192] = s3;
                    }
                }
            }
        }
    }
}

// ---- sim: S = qcat @ kcat^T per bh (K'=384 = 6-term split), triangle tiles -----------
// S packed per bh as 36 tiles of 64x64 fp32 (tile id = ti*(ti+1)/2 + tj).
__global__ __launch_bounds__(256) void mfma_sim(const unsigned short* __restrict__ qcat,
                                                const unsigned short* __restrict__ kcat,
                                                float* __restrict__ S) {
    __shared__ unsigned short Ab[2 * 64 * 72];
    __shared__ unsigned short Bb[2 * 64 * 72];
    const int bh = blockIdx.y;
    const int ti = TI[blockIdx.x], tj = TJ[blockIdx.x];
    f32x4 acc[2][2] = {};
    gemm_core(qcat + ((size_t)bh * Tn + ti * 64) * 384,
              kcat + ((size_t)bh * Tn + tj * 64) * 384, 384, 6, Ab, Bb, acc);

    const int wv = threadIdx.x >> 6, lane = threadIdx.x & 63;
    const int kq = lane >> 4, r = lane & 15;
    float* Sp = S + (size_t)bh * 147456 + (size_t)(ti * (ti + 1) / 2 + tj) * 4096;
    #pragma unroll
    for (int mi = 0; mi < 2; ++mi)
        #pragma unroll
        for (int ni = 0; ni < 2; ++ni)
            #pragma unroll
            for (int rr = 0; rr < 4; ++rr) {
                int ml = (wv >> 1) * 32 + mi * 16 + kq * 4 + rr;
                int nl = (wv & 1) * 32 + ni * 16 + r;
                Sp[ml * 64 + nl] = acc[mi][ni][rr];
            }
}

// ---- proj: out = ybf @ Wpbf^T + bias (K=768) -----------------------------------------
__global__ __launch_bounds__(256) void mfma_proj(const unsigned short* __restrict__ Abf,
                                                 const unsigned short* __restrict__ Bbf,
                                                 const float* __restrict__ bias,
                                                 float* __restrict__ outp) {
    __shared__ unsigned short Ab[2 * 64 * 72];
    __shared__ unsigned short Bb[2 * 64 * 72];
    const int tm = blockIdx.x * 64;
    const int tn = blockIdx.y * 64;
    f32x4 acc[2][2] = {};
    gemm_core(Abf + (size_t)tm * Cn, Bbf + (size_t)tn * Cn, Cn, 12, Ab, Bb, acc);

    const int wv = threadIdx.x >> 6, lane = threadIdx.x & 63;
    const int kq = lane >> 4, r = lane & 15;
    #pragma unroll
    for (int mi = 0; mi < 2; ++mi)
        #pragma unroll
        for (int ni = 0; ni < 2; ++ni)
            #pragma unroll
            for (int rr = 0; rr < 4; ++rr) {
                int mm = tm + (wv >> 1) * 32 + mi * 16 + kq * 4 + rr;
                int nn = tn + (wv & 1) * 32 + ni * 16 + r;
                outp[(size_t)mm * Cn + nn] = acc[mi][ni][rr] + bias[nn];
            }
}

// ---- DPP selection: one WAVE per token, barrier-free ---------------------------------
__global__ __launch_bounds__(256) void dpp_kernel(const float* __restrict__ S,
                                                  const unsigned short* __restrict__ kcat,
                                                  const float* __restrict__ vh,
                                                  unsigned short* __restrict__ yb) {
    const int bh = blockIdx.x;
    const int w = threadIdx.x >> 6;
    const int lane = threadIdx.x & 63;
    const int i = blockIdx.y * 4 + w;

    __shared__ __align__(16) char smem[22944];
    float (*KshW)[68] = (float (*)[68])(smem + 2448 * w);              // [0,9792)
    float (*VshW)[65] = (float (*)[65])(smem + 9792 + 2340 * w);       // [9792,19152)
    float* GshW       = (float*)(smem + 19152 + 324 * w);              // [19152,20448)
    float* qdW        = (float*)(smem + 20448 + 48 * w);               // [20448,20640)
    float (*PWW)[4]   = (float (*)[4])(smem + 20640 + 576 * w);        // [20640,22944)

    const float* Sbh = S + (size_t)bh * 147456;
    const unsigned short* kc = kcat + (size_t)bh * Tn * 384;
    const float* vbase = vh + (size_t)bh * Tn * HS;

    const int ti = i >> 6;
    const int tribase = ti * (ti + 1) / 2;
    const int rloc = (i & 63) * 64;

    float sv[8];
    #pragma unroll
    for (int rr = 0; rr < 8; ++rr) {
        sv[rr] = -INFINITY;
        if (rr <= ti) {
            int j = rr * 64 + lane;
            float s = Sbh[(size_t)(tribase + rr) * 4096 + rloc + lane];
            sv[rr] = (j <= i) ? s : -INFINITY;
        }
    }

    // qd0 = sim[i][i]
    float qd0 = 0.f;
    #pragma unroll
    for (int c = 0; c < 8; ++c) {
        float t = __shfl(sv[c], i & 63, 64);
        if (c == ti) qd0 = t;
    }

    // top-8: 8 butterfly argmax passes (value desc, tie -> lower index)
    float topv[8]; int topi[8];
    #pragma unroll
    for (int p = 0; p < MTOP; ++p) {
        float bv = -INFINITY; int bi = 0x7fffffff;
        #pragma unroll
        for (int r = 0; r < 8; ++r) {
            int j = r * 64 + lane;
            float v = sv[r];
            if (v > bv || (v == bv && j < bi)) { bv = v; bi = j; }
        }
        #pragma unroll
        for (int off = 32; off > 0; off >>= 1) {
            float ov = __shfl_xor(bv, off, 64);
            int   oi = __shfl_xor(bi, off, 64);
            if (ov > bv || (ov == bv && oi < bi)) { bv = ov; bi = oi; }
        }
        topv[p] = bv; topi[p] = bi;
        const int rs = bi >> 6, ls = bi & 63;
        #pragma unroll
        for (int r = 0; r < 8; ++r)
            if (r == rs && lane == ls) sv[r] = -INFINITY;
    }

    const int n_cand = (i + 1 < MTOP) ? (i + 1) : MTOP;
    int vmask = 0;
    #pragma unroll
    for (int s = 0; s < MTOP; ++s)
        if (s < n_cand && topi[s] != i) vmask |= (1 << s);

    // stage selected K/V rows {i} U top_idx (lane = d); k reconstructed from 3 splits
    #pragma unroll
    for (int a = 0; a < 9; ++a) {
        int t = (a == 0) ? i : topi[a - 1];
        size_t kb = (size_t)t * 384 + lane;
        KshW[a][lane] = bf_f(kc[kb]) + bf_f(kc[kb + 64]) + bf_f(kc[kb + 192]);
        VshW[a][lane] = vbase[(size_t)t * HS + lane];
    }
    if (lane < 9) {
        float val = qd0;
        #pragma unroll
        for (int p = 0; p < 8; ++p) if (lane == p + 1) val = topv[p];
        qdW[lane] = val;
    }

    // gram: lane l < 45 computes pair (PA[l], PB[l]) (per-wave LDS, no barrier)
    if (lane < 45) {
        const int a = PA[lane], b = PB[lane];
        const float4* rka = (const float4*)&KshW[a][0];
        const float4* rkb = (const float4*)&KshW[b][0];
        float acc = 0.f;
        #pragma unroll
        for (int t = 0; t < 16; ++t) {
            float4 fa = rka[t], fb = rkb[t];
            acc += fa.x * fb.x; acc += fa.y * fb.y;
            acc += fa.z * fb.z; acc += fa.w * fb.w;
        }
        GshW[a * 9 + b] = acc;
        GshW[b * 9 + a] = acc;
    }

    // combos on lanes 0..35
    float score = -INFINITY;
    int ca = 0, cb = 0, sdim = 1;
    if (lane < NCOMB) {
        const int sl0 = C_SL0[lane], sl1 = C_SL1[lane];
        sdim = (sl1 < 0) ? 1 : 2;
        ca = sl0 + 1;
        cb = (sl1 < 0) ? 0 : sl1 + 1;
        bool valid = ((vmask >> sl0) & 1);
        if (sdim == 2) valid = valid && ((vmask >> sl1) & 1);
        float G00 = GshW[0];
        float Gaa = GshW[ca * 9 + ca];
        float G0a = GshW[ca];
        float det;
        if (sdim == 1) {
            det = G00 * Gaa - G0a * G0a;
        } else {
            float G0b = GshW[cb];
            float Gab = GshW[ca * 9 + cb];
            float Gbb = GshW[cb * 9 + cb];
            det = G00 * (Gaa * Gbb - Gab * Gab)
                - G0a * (G0a * Gbb - Gab * G0b)
                + G0b * (G0a * Gab - Gaa * G0b);
        }
        score = valid ? (logf(det + 1e-6f) / (float)(sdim + 1)) : NEGV;
    }
    float mx = score;
    #pragma unroll
    for (int off = 32; off > 0; off >>= 1) mx = fmaxf(mx, __shfl_xor(mx, off, 64));
    float e = (lane < NCOMB) ? expf(score - mx) : 0.f;
    float sum = e;
    #pragma unroll
    for (int off = 32; off > 0; off >>= 1) sum += __shfl_xor(sum, off, 64);
    const bool hasValid = (mx > -1e29f);

    if (lane < NCOMB) {
        float prob = e / sum;
        float d0 = qdW[0]  * 0.125f;
        float d1 = qdW[ca] * 0.125f;
        float d2 = (sdim == 2) ? qdW[cb] * 0.125f : -INFINITY;
        float m2 = fmaxf(fmaxf(d0, d1), d2);
        float e0 = expf(d0 - m2), e1 = expf(d1 - m2);
        float e2 = (sdim == 2) ? expf(d2 - m2) : 0.f;
        float inv = prob / (e0 + e1 + e2);
        float4 pw = {e0 * inv, e1 * inv, e2 * inv, 0.f};
        *(float4*)&PWW[lane][0] = pw;
    }

    const float v0 = VshW[0][lane];
    float y;
    if (!hasValid) {
        y = v0;
    } else {
        float acc = 0.f;
        #pragma unroll
        for (int c = 0; c < NCOMB; ++c) {
            float4 pw = *(const float4*)&PWW[c][0];
            int a = C_SL0[c] + 1;
            int b = (C_SL1[c] < 0) ? 0 : C_SL1[c] + 1;
            acc += pw.x * v0 + pw.y * VshW[a][lane] + pw.z * VshW[b][lane];
        }
        y = acc;
    }
    const int bb = bh / Hn, h = bh % Hn;
    yb[((size_t)(bb * Tn + i)) * Cn + h * HS + lane] = bf_rne(y);
}

extern "C" void kernel_launch(void* const* d_in, const int* in_sizes, int n_in,
                              void* d_out, int out_size, void* d_ws, size_t ws_size,
                              hipStream_t stream) {
    const float* x      = (const float*)d_in[0];
    const float* W_attn = (const float*)d_in[1];
    const float* b_attn = (const float*)d_in[2];
    const float* W_proj = (const float*)d_in[3];
    const float* b_proj = (const float*)d_in[4];
    float* out = (float*)d_out;

    char* ws = (char*)d_ws;
    float* vh            = (float*)(ws);                          //  0        3 MB
    unsigned short* qcat = (unsigned short*)(ws + 3145728);       //  3 MB     9 MB
    unsigned short* kcat = (unsigned short*)(ws + 12582912);      // 12 MB     9 MB
    unsigned short* xcat = (unsigned short*)(ws + 22020096);      // 21 MB     4.5 MB (dead after qkv)
    unsigned short* Wcat = (unsigned short*)(ws + 26738688);      // 25.5 MB  10.125 MB (dead after qkv)
    float* S             = (float*)(ws + 26738688);               // overlays Wcat, 13.5 MB
    unsigned short* ybf  = xcat;                                  // overlays xcat after qkv
    unsigned short* Wpbf = (unsigned short*)(ws + 40894464);      // 39 MB     1.125 MB -> 40.1 MB total

    const int NX = Bn * Tn * Cn;   // 786432
    const int NW = 3 * Cn * Cn;    // 1769472
    const int NP = Cn * Cn;        // 589824

    // 1) split-convert into concatenated-K layouts
    //    xcat = [xhi | xhi | xlo]  (hi dup at +768, lo at +1536)
    //    Wcat = [Whi | Wlo | Whi]  (hi dup at +1536, lo at +768)
    conv_cat<<<dim3((NX + 255) / 256), 256, 0, stream>>>(x, xcat, NX, 768, 1536);
    conv_cat<<<dim3((NW + 255) / 256), 256, 0, stream>>>(W_attn, Wcat, NW, 1536, 768);

    // 2) qkv as ONE bf16 GEMM, K'=2304; scatter epilogue (q/k 3-way-split cat, v fp32)
    mfma_qkv<<<dim3(16, 36), 256, 0, stream>>>(xcat, Wcat, b_attn, qcat, kcat, vh);

    // 3) S = qcat @ kcat^T (K'=384, 6-term split), lower-triangle tiles, packed store
    mfma_sim<<<dim3(36, BH), 256, 0, stream>>>(qcat, kcat, S);

    // 4) W_proj -> bf16
    conv_bf<<<dim3((NP + 255) / 256), 256, 0, stream>>>(W_proj, Wpbf, NP);

    // 5) dpp: one wave per (head, token), barrier-free, reads packed S rows
    dpp_kernel<<<dim3(BH, Tn / 4), 256, 0, stream>>>(S, kcat, vh, ybf);

    // 6) out = y @ Wp^T + bias
    mfma_proj<<<dim3(16, 12), 256, 0, stream>>>(ybf, Wpbf, b_proj, out);
}